// Round 10
// baseline (173.809 us; speedup 1.0000x reference)
//
#include <hip/hip_runtime.h>

// Problem constants: B=4, L=2048, C=64, D=4
#define BB 4
#define LL 2048
#define CC 64
#define DD 4
#define AN (CC * DD)        // 256 A-entries per timestep per batch (c*4+i)
#define TPB 1024            // threads per block (16 waves)
#define N4PB 4              // n4 values per block
#define NSEGS (TPB / N4PB)  // 256 time segments per chain
#define TT (LL / NSEGS)     // 8 timesteps per thread

typedef float f32x4 __attribute__((ext_vector_type(4)));

// ---------------------------------------------------------------------------
// One-dispatch pscan, v6. Key change vs v4/v5 (which the compiler defeated by
// spilling X at TPB=1024): NOTHING bulky stays live across the scan.
//   pass 1: stream A,X once; the running local scan s IS y_loc -> store it to
//           out immediately; keep only pprod[t] (running A-product, 16 VGPR).
//   scan  : 8-round LDS Hillis-Steele on (p, s_final) tuples (as before).
//   pass 2: out RMW: y[t] = y_loc[t] + pprod[t]*carry. Reads are the block's
//           own just-written lines (L2/LLC-warm); each thread touches only its
//           own addresses; the vmcnt(0) drain at __syncthreads orders pass-1
//           stores before pass-2 loads. tseg==0 (carry=0) skips pass 2.
// Live state ~50 VGPR -> fits the compiler's 64-VGPR/8-waves-EU target with
// ZERO spill (v5 measured: VGPR=64 + 15 MB spill writes + 8 MB re-reads).
// Quad-lane 64 B line coalescing and chunked XCD swizzle retained.
// ---------------------------------------------------------------------------
__global__ __launch_bounds__(TPB) void pscan_onepass6(
    const float* __restrict__ A_re, const float* __restrict__ A_im,
    const f32x4* __restrict__ X_re4, const f32x4* __restrict__ X_im4,
    f32x4* __restrict__ out4) {
  // Chunked XCD swizzle (bijective on [0,256)): the 4 consecutive sids that
  // share each 64 B A-line land on the same XCD's L2.
  const int sid = (blockIdx.x & 7) * 32 + (blockIdx.x >> 3);
  const int b    = sid >> 6;                 // [0,4)
  const int n4g  = sid & 63;                 // [0,64)
  const int tid  = threadIdx.x;
  const int n4l  = tid & (N4PB - 1);
  const int tseg = tid >> 2;                 // [0,256)
  const int n4   = n4g * N4PB + n4l;
  const int t0   = tseg * TT;
  const int base = (b * LL + t0) * AN + n4;  // index for A (float) and X (f32x4)
  const int ob   = (b * LL + t0) * (2 * AN) + n4 * 2;  // f32x4 index into out

  // ---- pass 1: stream A,X; write y_loc to out; keep pprod trajectory ----
  float pp_re[TT], pp_im[TT];
  float p_re = 1.f, p_im = 0.f;
  float s_re[4] = {0.f, 0.f, 0.f, 0.f};
  float s_im[4] = {0.f, 0.f, 0.f, 0.f};
#pragma unroll
  for (int t = 0; t < TT; ++t) {
    const float are = A_re[base + t * AN];
    const float aim = A_im[base + t * AN];
    const f32x4 xr = X_re4[base + t * AN];
    const f32x4 xi = X_im4[base + t * AN];
    const float npre = are * p_re - aim * p_im;
    const float npim = are * p_im + aim * p_re;
    p_re = npre; p_im = npim;
    pp_re[t] = p_re; pp_im[t] = p_im;
#pragma unroll
    for (int j = 0; j < 4; ++j) {
      const float nsre = are * s_re[j] - aim * s_im[j] + xr[j];
      const float nsim = are * s_im[j] + aim * s_re[j] + xi[j];
      s_re[j] = nsre; s_im[j] = nsim;
    }
    // s after step t == zero-seeded local scan y_loc[t]: store it now.
    f32x4 o0 = {s_re[0], s_im[0], s_re[1], s_im[1]};
    f32x4 o1 = {s_re[2], s_im[2], s_re[3], s_im[3]};
    out4[ob + t * (2 * AN)]     = o0;
    out4[ob + t * (2 * AN) + 1] = o1;
  }

  // ---- block-level inclusive Hillis-Steele scan (per n4 group) ----
  // tuple q = tid, 11-float stride (11 coprime 32): worst aliasing 2-way
  // (lane i vs i+32) = free on CDNA4.
  __shared__ float lds[TPB * 11];
  const int q = tid * 11;
  lds[q + 0] = p_re; lds[q + 1] = p_im;
#pragma unroll
  for (int j = 0; j < 4; ++j) { lds[q + 2 + j] = s_re[j]; lds[q + 6 + j] = s_im[j]; }

  float vp_re = p_re, vp_im = p_im;
  float vs_re[4], vs_im[4];
#pragma unroll
  for (int j = 0; j < 4; ++j) { vs_re[j] = s_re[j]; vs_im[j] = s_im[j]; }

  for (int d = 1; d < NSEGS; d <<= 1) {
    __syncthreads();
    float wp_re = 1.f, wp_im = 0.f;
    float ws_re[4] = {0.f, 0.f, 0.f, 0.f};
    float ws_im[4] = {0.f, 0.f, 0.f, 0.f};
    if (tseg >= d) {
      const int q2 = q - d * (N4PB * 11);    // (tseg-d, same n4l)
      wp_re = lds[q2 + 0]; wp_im = lds[q2 + 1];
#pragma unroll
      for (int j = 0; j < 4; ++j) { ws_re[j] = lds[q2 + 2 + j]; ws_im[j] = lds[q2 + 6 + j]; }
    }
    __syncthreads();
    if (tseg >= d) {
      // combine(earlier = w, later = v): p' = vp*wp ; s' = vp*ws + vs
      const float np_re = vp_re * wp_re - vp_im * wp_im;
      const float np_im = vp_re * wp_im + vp_im * wp_re;
#pragma unroll
      for (int j = 0; j < 4; ++j) {
        const float ns_re = vp_re * ws_re[j] - vp_im * ws_im[j] + vs_re[j];
        const float ns_im = vp_re * ws_im[j] + vp_im * ws_re[j] + vs_im[j];
        vs_re[j] = ns_re; vs_im[j] = ns_im;
      }
      vp_re = np_re; vp_im = np_im;
      lds[q + 0] = vp_re; lds[q + 1] = vp_im;
#pragma unroll
      for (int j = 0; j < 4; ++j) { lds[q + 2 + j] = vs_re[j]; lds[q + 6 + j] = vs_im[j]; }
    }
  }
  __syncthreads();

  // ---- pass 2: out RMW with carry (tseg 0 has carry=0: already correct) ----
  if (tseg > 0) {
    const int qc = q - N4PB * 11;            // inclusive tuple of tseg-1
    float cy_re[4], cy_im[4];
#pragma unroll
    for (int j = 0; j < 4; ++j) { cy_re[j] = lds[qc + 2 + j]; cy_im[j] = lds[qc + 6 + j]; }
#pragma unroll
    for (int t = 0; t < TT; ++t) {
      f32x4 o0 = out4[ob + t * (2 * AN)];
      f32x4 o1 = out4[ob + t * (2 * AN) + 1];
      const float wr = pp_re[t], wi = pp_im[t];
      o0.x += wr * cy_re[0] - wi * cy_im[0];
      o0.y += wr * cy_im[0] + wi * cy_re[0];
      o0.z += wr * cy_re[1] - wi * cy_im[1];
      o0.w += wr * cy_im[1] + wi * cy_re[1];
      o1.x += wr * cy_re[2] - wi * cy_im[2];
      o1.y += wr * cy_im[2] + wi * cy_re[2];
      o1.z += wr * cy_re[3] - wi * cy_im[3];
      o1.w += wr * cy_im[3] + wi * cy_re[3];
      out4[ob + t * (2 * AN)]     = o0;
      out4[ob + t * (2 * AN) + 1] = o1;
    }
  }
}

extern "C" void kernel_launch(void* const* d_in, const int* in_sizes, int n_in,
                              void* d_out, int out_size, void* d_ws, size_t ws_size,
                              hipStream_t stream) {
  const float* A_re  = (const float*)d_in[0];
  const float* A_im  = (const float*)d_in[1];
  const f32x4* X_re4 = (const f32x4*)d_in[2];
  const f32x4* X_im4 = (const f32x4*)d_in[3];
  f32x4* out4 = (f32x4*)d_out;
  (void)d_ws; (void)ws_size;  // no workspace needed

  const int blocks = BB * (AN / N4PB);   // 256 blocks: one per (b, 4-n4 group)
  pscan_onepass6<<<blocks, TPB, 0, stream>>>(A_re, A_im, X_re4, X_im4, out4);
}

// Round 11
// 162.603 us; speedup vs baseline: 1.0689x; 1.0689x over previous
//
#include <hip/hip_runtime.h>

// Problem constants: B=4, L=2048, C=64, D=4
#define BB 4
#define LL 2048
#define CC 64
#define DD 4
#define AN (CC * DD)        // 256 A-entries per timestep per batch (c*4+i)
#define TPB 512             // threads per block (8 waves)
#define N4PB 2              // n4 values per block
#define NSEGS (TPB / N4PB)  // 256 time segments per chain
#define TT (LL / NSEGS)     // 8 timesteps per thread

typedef float f32x4 __attribute__((ext_vector_type(4)));

// ---------------------------------------------------------------------------
// One-dispatch pscan, v7. Geometry chosen from three measured constraints:
//  (1) X must be register-resident across the scan (re-touch of X or out
//      through memory costs 25-35 us: v3 remat / v6 RMW both measured).
//  (2) TPB=1024 forces the 64-VGPR tier and spills (v4/v5 measured);
//      TPB=512 naturally sits at the 128-VGPR/4-waves-EU tier (v3: 124).
//  (3) 1 block/CU serializes scan barriers with nothing to overlap (v3's
//      50 us). Need >= 2 blocks/CU.
// => N4PB=2: TPB=512, TT=8 -> X=64 VGPR + A=16 + state ~36 = ~116 VGPR;
//    full chain per block; 512 blocks = 2/CU = 16 waves/CU.
// Cost: X loads are 32 B half-lines (lane pairs). The other half of each
// 64 B line belongs to the ADJACENT n4g block -> XCD swizzle co-locates it
// on the same L2, so HBM still sees each line once. Stores remain full
// 64 B per lane pair. Zero workspace, no inter-block sync.
// ---------------------------------------------------------------------------
__global__ __launch_bounds__(TPB) void pscan_onepass7(
    const float* __restrict__ A_re, const float* __restrict__ A_im,
    const f32x4* __restrict__ X_re4, const f32x4* __restrict__ X_im4,
    f32x4* __restrict__ out4) {
  // Chunked XCD swizzle, bijective on [0,512): XCD k owns sids [64k, 64k+64)
  // -> adjacent-n4g blocks (sharing X lines and A lines) on the same L2.
  const int sid = (blockIdx.x & 7) * 64 + (blockIdx.x >> 3);
  const int b    = sid >> 7;                 // [0,4)
  const int n4g  = sid & 127;                // [0,128)
  const int tid  = threadIdx.x;
  const int n4l  = tid & (N4PB - 1);         // [0,2)
  const int tseg = tid >> 1;                 // [0,256)
  const int n4   = n4g * N4PB + n4l;
  const int t0   = tseg * TT;
  const int base = (b * LL + t0) * AN + n4;  // index for A (float) and X (f32x4)

  // ---- pass 1: load A,X into registers; compute segment aggregate ----
  float ar[TT], ai[TT];
  f32x4 xr[TT], xi[TT];
  float p_re = 1.f, p_im = 0.f;
  float s_re[4] = {0.f, 0.f, 0.f, 0.f};
  float s_im[4] = {0.f, 0.f, 0.f, 0.f};
#pragma unroll
  for (int t = 0; t < TT; ++t) {
    const float are = A_re[base + t * AN];
    const float aim = A_im[base + t * AN];
    ar[t] = are; ai[t] = aim;
    xr[t] = X_re4[base + t * AN];
    xi[t] = X_im4[base + t * AN];
    const float npre = are * p_re - aim * p_im;
    const float npim = are * p_im + aim * p_re;
    p_re = npre; p_im = npim;
#pragma unroll
    for (int j = 0; j < 4; ++j) {
      const float nsre = are * s_re[j] - aim * s_im[j] + xr[t][j];
      const float nsim = are * s_im[j] + aim * s_re[j] + xi[t][j];
      s_re[j] = nsre; s_im[j] = nsim;
    }
  }

  // ---- block-level inclusive Hillis-Steele scan (per n4l chain) ----
  // tuple q = tid, 11-float stride (11 coprime 32): worst aliasing 2-way
  // (lane i vs i+32) = free on CDNA4. 8 rounds (d = 1..128).
  __shared__ float lds[TPB * 11];
  const int q = tid * 11;
  lds[q + 0] = p_re; lds[q + 1] = p_im;
#pragma unroll
  for (int j = 0; j < 4; ++j) { lds[q + 2 + j] = s_re[j]; lds[q + 6 + j] = s_im[j]; }

  float vp_re = p_re, vp_im = p_im;
  float vs_re[4], vs_im[4];
#pragma unroll
  for (int j = 0; j < 4; ++j) { vs_re[j] = s_re[j]; vs_im[j] = s_im[j]; }

  for (int d = 1; d < NSEGS; d <<= 1) {
    __syncthreads();
    float wp_re = 1.f, wp_im = 0.f;
    float ws_re[4] = {0.f, 0.f, 0.f, 0.f};
    float ws_im[4] = {0.f, 0.f, 0.f, 0.f};
    if (tseg >= d) {
      const int q2 = q - d * (N4PB * 11);    // (tseg-d, same n4l)
      wp_re = lds[q2 + 0]; wp_im = lds[q2 + 1];
#pragma unroll
      for (int j = 0; j < 4; ++j) { ws_re[j] = lds[q2 + 2 + j]; ws_im[j] = lds[q2 + 6 + j]; }
    }
    __syncthreads();
    if (tseg >= d) {
      // combine(earlier = w, later = v): p' = vp*wp ; s' = vp*ws + vs
      const float np_re = vp_re * wp_re - vp_im * wp_im;
      const float np_im = vp_re * wp_im + vp_im * wp_re;
#pragma unroll
      for (int j = 0; j < 4; ++j) {
        const float ns_re = vp_re * ws_re[j] - vp_im * ws_im[j] + vs_re[j];
        const float ns_im = vp_re * ws_im[j] + vp_im * ws_re[j] + vs_im[j];
        vs_re[j] = ns_re; vs_im[j] = ns_im;
      }
      vp_re = np_re; vp_im = np_im;
      lds[q + 0] = vp_re; lds[q + 1] = vp_im;
#pragma unroll
      for (int j = 0; j < 4; ++j) { lds[q + 2 + j] = vs_re[j]; lds[q + 6 + j] = vs_im[j]; }
    }
  }
  __syncthreads();

  // ---- exclusive carry = inclusive value of segment tseg-1 (same n4l) ----
  float y_re[4] = {0.f, 0.f, 0.f, 0.f};
  float y_im[4] = {0.f, 0.f, 0.f, 0.f};
  if (tseg > 0) {
    const int qc = q - N4PB * 11;
#pragma unroll
    for (int j = 0; j < 4; ++j) { y_re[j] = lds[qc + 2 + j]; y_im[j] = lds[qc + 6 + j]; }
  }

  // ---- pass 2: apply carry from registers, store (64 B per lane pair) ----
  const int ob = (b * LL + t0) * (2 * AN) + n4 * 2;  // f32x4 index into out
#pragma unroll
  for (int t = 0; t < TT; ++t) {
    const float are = ar[t], aim = ai[t];
#pragma unroll
    for (int j = 0; j < 4; ++j) {
      const float ny_re = are * y_re[j] - aim * y_im[j] + xr[t][j];
      const float ny_im = are * y_im[j] + aim * y_re[j] + xi[t][j];
      y_re[j] = ny_re; y_im[j] = ny_im;
    }
    f32x4 o0 = {y_re[0], y_im[0], y_re[1], y_im[1]};
    f32x4 o1 = {y_re[2], y_im[2], y_re[3], y_im[3]};
    out4[ob + t * (2 * AN)]     = o0;
    out4[ob + t * (2 * AN) + 1] = o1;
  }
}

extern "C" void kernel_launch(void* const* d_in, const int* in_sizes, int n_in,
                              void* d_out, int out_size, void* d_ws, size_t ws_size,
                              hipStream_t stream) {
  const float* A_re  = (const float*)d_in[0];
  const float* A_im  = (const float*)d_in[1];
  const f32x4* X_re4 = (const f32x4*)d_in[2];
  const f32x4* X_im4 = (const f32x4*)d_in[3];
  f32x4* out4 = (f32x4*)d_out;
  (void)d_ws; (void)ws_size;  // no workspace needed

  const int blocks = BB * (AN / N4PB);   // 512 blocks: one per (b, 2-n4 group)
  pscan_onepass7<<<blocks, TPB, 0, stream>>>(A_re, A_im, X_re4, X_im4, out4);
}